// Round 10
// baseline (89.391 us; speedup 1.0000x reference)
//
#include <hip/hip_runtime.h>

#define Bn 1024
#define Pn 128
#define Fn 512
#define Dn 256
#define THETA 1e-7f
#define BP (Bn * Pn)
#define SB 8            // F-split of main kernel
#define FCB (Fn / SB)   // 64
#define NGRP 64         // output-tile groups = (Bn/64)*(Pn/32)

typedef _Float16 f16;
typedef f16 f16x8 __attribute__((ext_vector_type(8)));
typedef f16 f16x4 __attribute__((ext_vector_type(4)));
typedef f16 f16x2 __attribute__((ext_vector_type(2)));

#if defined(__has_builtin)
#if __has_builtin(__builtin_amdgcn_fdot2)
#define FDOT2(a, b, c) __builtin_amdgcn_fdot2((a), (b), (c), false)
#endif
#endif
#ifndef FDOT2
#define FDOT2(a, b, c) ((float)(a)[0] * (float)(b)[0] + (float)(a)[1] * (float)(b)[1] + (c))
#endif

// Extract f16x2 sub-vector `idx` (0..3) of an f16x8. With fully unrolled
// callers idx is compile-time constant -> stays in registers.
__device__ __forceinline__ f16x2 get2(const f16x8 v, int idx) {
    union { f16x8 v8; f16x2 v2[4]; } u;
    u.v8 = v;
    return u.v2[idx];
}

// ---------------------------------------------------------------------------
// K1: exact f32 GEMM [x; prototypes] @ fb^T (round-1 body, proven).
// Epilogue emits f16 relu-values + 0/1 masks (masks from EXACT f32):
//   rows <  Bn: RX[b][F], BX[b][F]            (row-major f16)
//   rows >= Bn: RPT2/BPT2 [F/2][P][2]         (f-pair interleaved, transposed)
// Also zeroes the NGRP ticket counters for K2 (block (0,0), tid<NGRP).
// ---------------------------------------------------------------------------
__global__ __launch_bounds__(256)
void gemm_feat(const float* __restrict__ x, const float* __restrict__ prot,
               const float* __restrict__ fb,
               f16* __restrict__ RX, f16* __restrict__ BX,
               f16* __restrict__ RPT2, f16* __restrict__ BPT2,
               unsigned* __restrict__ cnt)
{
    __shared__ float As[64][68];
    __shared__ float Fs[64][68];
    const int tid = threadIdx.x;
    const int rb  = blockIdx.y * 64;
    const int cb  = blockIdx.x * 64;
    const int tx  = tid & 15;
    const int ty  = tid >> 4;
    const int lr  = tid >> 2;
    const int lk  = tid & 3;

    if (blockIdx.x == 0 && blockIdx.y == 0 && tid < NGRP) cnt[tid] = 0;

    float acc[4][4] = {};

    for (int k0 = 0; k0 < Dn; k0 += 64) {
        #pragma unroll
        for (int q = 0; q < 4; ++q) {
            const int kk = lk + q * 4;
            const int r  = rb + lr;
            const float* asrc = (r < Bn) ? (x + (size_t)r * Dn)
                                         : (prot + (size_t)(r - Bn) * Dn);
            float4 av = *(const float4*)(asrc + k0 + kk * 4);
            float4 fv = *(const float4*)(fb + (size_t)(cb + lr) * Dn + k0 + kk * 4);
            As[kk*4+0][lr] = av.x; As[kk*4+1][lr] = av.y;
            As[kk*4+2][lr] = av.z; As[kk*4+3][lr] = av.w;
            Fs[kk*4+0][lr] = fv.x; Fs[kk*4+1][lr] = fv.y;
            Fs[kk*4+2][lr] = fv.z; Fs[kk*4+3][lr] = fv.w;
        }
        __syncthreads();
        #pragma unroll 8
        for (int k = 0; k < 64; ++k) {
            float4 a = *(const float4*)&As[k][ty * 4];
            float4 f = *(const float4*)&Fs[k][tx * 4];
            const float aa[4] = {a.x, a.y, a.z, a.w};
            const float ff[4] = {f.x, f.y, f.z, f.w};
            #pragma unroll
            for (int i = 0; i < 4; ++i)
                #pragma unroll
                for (int j = 0; j < 4; ++j)
                    acc[i][j] = fmaf(aa[i], ff[j], acc[i][j]);
        }
        __syncthreads();
    }

    #pragma unroll
    for (int i = 0; i < 4; ++i) {
        const int r = rb + ty * 4 + i;
        if (r < Bn) {
            f16x4 rv, bv;
            #pragma unroll
            for (int j = 0; j < 4; ++j) {
                const float v = acc[i][j];
                rv[j] = (f16)fmaxf(v, 0.f);
                bv[j] = (v > 0.f) ? (f16)1 : (f16)0;
            }
            const size_t off = (size_t)r * Fn + cb + tx * 4;
            *(f16x4*)(RX + off) = rv;
            *(f16x4*)(BX + off) = bv;
        } else {
            const int p = r - Bn;
            #pragma unroll
            for (int j = 0; j < 4; ++j) {
                const int c = cb + tx * 4 + j;
                const float v = acc[i][j];
                const size_t off = (size_t)(c >> 1) * (Pn * 2) + p * 2 + (c & 1);
                RPT2[off] = (f16)fmaxf(v, 0.f);
                BPT2[off] = (v > 0.f) ? (f16)1 : (f16)0;
            }
        }
    }
}

// ---------------------------------------------------------------------------
// K2: Tversky main (round-1 proven shape) on f16 via v_dot2_f32_f16.
//  Per thread (2b x 4p), per f-pair:
//   I += dot2(rx2, rp2); M += dot2(min(rx2,rp2), 1); X += dot2(rx2, bp2);
//   P += dot2(bx2, rp2)   -- all f32 accumulation, 2.5 lane-ops/pair-f.
//  Grid (16,4,SB) = 512 blocks. Last S-sibling per (bx,py) group sums the
//  SB partials (fixed order -> deterministic) and writes the ratio.
// ---------------------------------------------------------------------------
__global__ __launch_bounds__(256)
void tversky_main(const f16* __restrict__ RX, const f16* __restrict__ BX,
                  const f16* __restrict__ RPT2, const f16* __restrict__ BPT2,
                  const float* __restrict__ alpha_p, const float* __restrict__ beta_p,
                  float* __restrict__ partI, float* __restrict__ partW,
                  unsigned* __restrict__ cnt, float* __restrict__ out)
{
    const int tid = threadIdx.x;
    const int tx  = tid & 7;
    const int ty  = tid >> 3;
    const int bb  = blockIdx.x * 64;
    const int pb  = blockIdx.y * 32;
    const int p0  = pb + tx * 4;
    const int b0  = bb + ty * 2;
    const int s   = blockIdx.z;
    const int f0  = s * FCB;

    float aI[2][4] = {};
    float aM[2][4] = {};
    float aX[2][4] = {};
    float aP[2][4] = {};

    const f16x2 one2 = {(f16)1, (f16)1};

    #pragma unroll 2
    for (int g = 0; g < FCB / 8; ++g) {          // 8 f's per iteration
        f16x8 rx8[2], bx8[2];
        #pragma unroll
        for (int i = 0; i < 2; ++i) {
            const size_t xo = (size_t)(b0 + i) * Fn + f0 + g * 8;
            rx8[i] = *(const f16x8*)(RX + xo);
            bx8[i] = *(const f16x8*)(BX + xo);
        }
        #pragma unroll
        for (int h = 0; h < 4; ++h) {            // f-pairs within the group
            const size_t po = (size_t)(f0 / 2 + g * 4 + h) * (Pn * 2) + (size_t)p0 * 2;
            const f16x8 rp8 = *(const f16x8*)(RPT2 + po);
            const f16x8 bp8 = *(const f16x8*)(BPT2 + po);
            #pragma unroll
            for (int i = 0; i < 2; ++i) {
                const f16x2 rx2 = get2(rx8[i], h);
                const f16x2 bx2 = get2(bx8[i], h);
                #pragma unroll
                for (int q = 0; q < 4; ++q) {
                    const f16x2 rp2 = get2(rp8, q);
                    const f16x2 bp2 = get2(bp8, q);
                    aI[i][q] = FDOT2(rx2, rp2, aI[i][q]);
                    aM[i][q] = FDOT2(__builtin_elementwise_min(rx2, rp2), one2, aM[i][q]);
                    aX[i][q] = FDOT2(rx2, bp2, aX[i][q]);
                    aP[i][q] = FDOT2(bx2, rp2, aP[i][q]);
                }
            }
        }
    }

    const float alpha = *alpha_p;
    const float beta  = *beta_p;
    #pragma unroll
    for (int i = 0; i < 2; ++i) {
        #pragma unroll
        for (int q = 0; q < 4; ++q) {
            const size_t idx = (size_t)s * BP + (size_t)(b0 + i) * Pn + (p0 + q);
            partI[idx] = aI[i][q];
            partW[idx] = alpha * (aX[i][q] - aM[i][q])
                       + beta  * (aP[i][q] - aM[i][q]);
        }
    }

    // ---- last-block reduction (threadfence-reduction pattern) ----
    __threadfence();
    __syncthreads();
    __shared__ unsigned ticket;
    const int grp = blockIdx.x * 4 + blockIdx.y;
    if (tid == 0) ticket = atomicAdd(&cnt[grp], 1u);
    __syncthreads();
    if (ticket == SB - 1) {
        __threadfence();
        #pragma unroll
        for (int e = 0; e < 8; ++e) {            // 2048 outputs / 256 threads
            const int t   = e * 256 + tid;
            const int row = t >> 5;
            const int col = t & 31;
            const size_t idx = (size_t)(bb + row) * Pn + pb + col;
            float I = 0.f, W = 0.f;
            #pragma unroll
            for (int s2 = 0; s2 < SB; ++s2) {
                I += partI[(size_t)s2 * BP + idx];
                W += partW[(size_t)s2 * BP + idx];
            }
            out[idx] = I / (I + W + THETA);
        }
    }
}

extern "C" void kernel_launch(void* const* d_in, const int* in_sizes, int n_in,
                              void* d_out, int out_size, void* d_ws, size_t ws_size,
                              hipStream_t stream)
{
    const float* x     = (const float*)d_in[0];
    const float* prot  = (const float*)d_in[1];
    const float* fb    = (const float*)d_in[2];
    const float* alpha = (const float*)d_in[3];
    const float* beta  = (const float*)d_in[4];
    float* out = (float*)d_out;

    float*    partI = (float*)d_ws;                       // SB*BP f32
    float*    partW = partI + (size_t)SB * BP;            // SB*BP f32
    unsigned* cnt   = (unsigned*)(partW + (size_t)SB * BP); // NGRP u32
    f16*      RX    = (f16*)(cnt + 64);                   // Bn*Fn f16 (16B-aligned)
    f16*      BX    = RX + (size_t)Bn * Fn;
    f16*      RPT2  = BX + (size_t)Bn * Fn;               // (Fn/2)*Pn*2 f16
    f16*      BPT2  = RPT2 + (size_t)Fn * Pn;

    dim3 gg(Fn / 64, (Bn + Pn) / 64);                     // 8 x 18 = 144 blocks
    gemm_feat<<<gg, 256, 0, stream>>>(x, prot, fb, RX, BX, RPT2, BPT2, cnt);

    dim3 gm(Bn / 64, Pn / 32, SB);                        // 16 x 4 x 8 = 512 blocks
    tversky_main<<<gm, 256, 0, stream>>>(RX, BX, RPT2, BPT2, alpha, beta,
                                         partI, partW, cnt, out);
}

// Round 11
// 34.433 us; speedup vs baseline: 2.5961x; 2.5961x over previous
//
#include <hip/hip_runtime.h>

#define Bn 1024
#define Pn 128
#define Fn 512
#define Dn 256
#define THETA 1e-7f

typedef _Float16 f16;
typedef f16 f16x8 __attribute__((ext_vector_type(8)));
typedef f16 f16x4 __attribute__((ext_vector_type(4)));
typedef f16 f16x2 __attribute__((ext_vector_type(2)));

#if defined(__has_builtin)
#if __has_builtin(__builtin_amdgcn_fdot2)
#define FDOT2(a, b, c) __builtin_amdgcn_fdot2((a), (b), (c), false)
#endif
#endif
#ifndef FDOT2
#define FDOT2(a, b, c) ((float)(a)[0] * (float)(b)[0] + (float)(a)[1] * (float)(b)[1] + (c))
#endif

// Extract f16x2 sub-vector `idx` (0..3) of an f16x8; callers fully unrolled
// so idx is compile-time constant (stays in registers).
__device__ __forceinline__ f16x2 get2(const f16x8 v, int idx) {
    union { f16x8 v8; f16x2 v2[4]; } u;
    u.v8 = v;
    return u.v2[idx];
}

// ---------------------------------------------------------------------------
// K1: exact f32 GEMM [x; prototypes] @ fb^T (round-1 body, proven).
// Epilogue emits f16 relu-values + 0/1 masks (masks from EXACT f32):
//   rows <  Bn: RX[b][F], BX[b][F]          row-major f16
//   rows >= Bn: RPT8/BPT8 [F/8][P][8]       8-f groups per p contiguous
// ---------------------------------------------------------------------------
__global__ __launch_bounds__(256)
void gemm_feat(const float* __restrict__ x, const float* __restrict__ prot,
               const float* __restrict__ fb,
               f16* __restrict__ RX, f16* __restrict__ BX,
               f16* __restrict__ RPT8, f16* __restrict__ BPT8)
{
    __shared__ float As[64][68];
    __shared__ float Fs[64][68];
    const int tid = threadIdx.x;
    const int rb  = blockIdx.y * 64;
    const int cb  = blockIdx.x * 64;
    const int tx  = tid & 15;
    const int ty  = tid >> 4;
    const int lr  = tid >> 2;
    const int lk  = tid & 3;

    float acc[4][4] = {};

    for (int k0 = 0; k0 < Dn; k0 += 64) {
        #pragma unroll
        for (int q = 0; q < 4; ++q) {
            const int kk = lk + q * 4;
            const int r  = rb + lr;
            const float* asrc = (r < Bn) ? (x + (size_t)r * Dn)
                                         : (prot + (size_t)(r - Bn) * Dn);
            float4 av = *(const float4*)(asrc + k0 + kk * 4);
            float4 fv = *(const float4*)(fb + (size_t)(cb + lr) * Dn + k0 + kk * 4);
            As[kk*4+0][lr] = av.x; As[kk*4+1][lr] = av.y;
            As[kk*4+2][lr] = av.z; As[kk*4+3][lr] = av.w;
            Fs[kk*4+0][lr] = fv.x; Fs[kk*4+1][lr] = fv.y;
            Fs[kk*4+2][lr] = fv.z; Fs[kk*4+3][lr] = fv.w;
        }
        __syncthreads();
        #pragma unroll 8
        for (int k = 0; k < 64; ++k) {
            float4 a = *(const float4*)&As[k][ty * 4];
            float4 f = *(const float4*)&Fs[k][tx * 4];
            const float aa[4] = {a.x, a.y, a.z, a.w};
            const float ff[4] = {f.x, f.y, f.z, f.w};
            #pragma unroll
            for (int i = 0; i < 4; ++i)
                #pragma unroll
                for (int j = 0; j < 4; ++j)
                    acc[i][j] = fmaf(aa[i], ff[j], acc[i][j]);
        }
        __syncthreads();
    }

    #pragma unroll
    for (int i = 0; i < 4; ++i) {
        const int r = rb + ty * 4 + i;
        if (r < Bn) {
            f16x4 rv, bv;
            #pragma unroll
            for (int j = 0; j < 4; ++j) {
                const float v = acc[i][j];
                rv[j] = (f16)fmaxf(v, 0.f);
                bv[j] = (v > 0.f) ? (f16)1 : (f16)0;
            }
            const size_t off = (size_t)r * Fn + cb + tx * 4;
            *(f16x4*)(RX + off) = rv;
            *(f16x4*)(BX + off) = bv;
        } else {
            const int p = r - Bn;
            #pragma unroll
            for (int j = 0; j < 4; ++j) {
                const int c = cb + tx * 4 + j;
                const float v = acc[i][j];
                const size_t off = (size_t)(c >> 3) * (Pn * 8) + p * 8 + (c & 7);
                RPT8[off] = (f16)fmaxf(v, 0.f);
                BPT8[off] = (v > 0.f) ? (f16)1 : (f16)0;
            }
        }
    }
}

// ---------------------------------------------------------------------------
// K2: Tversky main, full F per thread (one output each) — no partials, no
// cross-block communication. Per f16x8 group (8 f's):
//   I += dot2(rx,rp)x4 ; M += dot2(min(rx,rp),1)x4 (relu'd => min>=0 exact);
//   X += dot2(rx,bp)x4 ; P += dot2(bx,rp)x4  -- all f32 accumulation.
// Block = 16b x 16p (256 thr). Grid (Bn/16, Pn/16) = 64 x 8 = 512 blocks
// -> 8 waves/CU. x-loads broadcast within 16-lane groups; p-loads 16B/lane,
// 256B contiguous per group (RPT8 layout). All data L2-resident (~2.5 MB).
// ---------------------------------------------------------------------------
__global__ __launch_bounds__(256)
void tversky_main(const f16* __restrict__ RX, const f16* __restrict__ BX,
                  const f16* __restrict__ RPT8, const f16* __restrict__ BPT8,
                  const float* __restrict__ alpha_p, const float* __restrict__ beta_p,
                  float* __restrict__ out)
{
    const int tid = threadIdx.x;
    const int b   = blockIdx.x * 16 + (tid >> 4);
    const int p   = blockIdx.y * 16 + (tid & 15);

    const f16* xrow  = RX + (size_t)b * Fn;
    const f16* bxrow = BX + (size_t)b * Fn;
    const f16* prow  = RPT8 + (size_t)p * 8;
    const f16* bprow = BPT8 + (size_t)p * 8;

    float aI = 0.f, aM = 0.f, aX = 0.f, aP = 0.f;
    const f16x2 one2 = {(f16)1, (f16)1};

    #pragma unroll 4
    for (int g = 0; g < Fn / 8; ++g) {
        const f16x8 rx = *(const f16x8*)(xrow  + g * 8);
        const f16x8 bx = *(const f16x8*)(bxrow + g * 8);
        const f16x8 rp = *(const f16x8*)(prow  + (size_t)g * (Pn * 8));
        const f16x8 bp = *(const f16x8*)(bprow + (size_t)g * (Pn * 8));
        const f16x8 mn = __builtin_elementwise_min(rx, rp);
        #pragma unroll
        for (int h = 0; h < 4; ++h) {
            aI = FDOT2(get2(rx, h), get2(rp, h), aI);
            aM = FDOT2(get2(mn, h), one2,        aM);
            aX = FDOT2(get2(rx, h), get2(bp, h), aX);
            aP = FDOT2(get2(bx, h), get2(rp, h), aP);
        }
    }

    const float alpha = *alpha_p;
    const float beta  = *beta_p;
    const float W = alpha * (aX - aM) + beta * (aP - aM);
    out[(size_t)b * Pn + p] = aI / (aI + W + THETA);
}

extern "C" void kernel_launch(void* const* d_in, const int* in_sizes, int n_in,
                              void* d_out, int out_size, void* d_ws, size_t ws_size,
                              hipStream_t stream)
{
    const float* x     = (const float*)d_in[0];
    const float* prot  = (const float*)d_in[1];
    const float* fb    = (const float*)d_in[2];
    const float* alpha = (const float*)d_in[3];
    const float* beta  = (const float*)d_in[4];
    float* out = (float*)d_out;

    f16* RX   = (f16*)d_ws;                   // Bn*Fn
    f16* BX   = RX + (size_t)Bn * Fn;         // Bn*Fn
    f16* RPT8 = BX + (size_t)Bn * Fn;         // Fn*Pn  ([F/8][P][8])
    f16* BPT8 = RPT8 + (size_t)Fn * Pn;       // Fn*Pn

    dim3 gg(Fn / 64, (Bn + Pn) / 64);         // 8 x 18 = 144 blocks
    gemm_feat<<<gg, 256, 0, stream>>>(x, prot, fb, RX, BX, RPT8, BPT8);

    dim3 gm(Bn / 16, Pn / 16);                // 64 x 8 = 512 blocks
    tversky_main<<<gm, 256, 0, stream>>>(RX, BX, RPT8, BPT8, alpha, beta, out);
}

// Round 12
// 33.153 us; speedup vs baseline: 2.6963x; 1.0386x over previous
//
#include <hip/hip_runtime.h>

#define Bn 1024
#define Pn 128
#define Fn 512
#define Dn 256
#define THETA 1e-7f

typedef _Float16 f16;
typedef f16 f16x8 __attribute__((ext_vector_type(8)));
typedef f16 f16x4 __attribute__((ext_vector_type(4)));
typedef f16 f16x2 __attribute__((ext_vector_type(2)));

#if defined(__has_builtin)
#if __has_builtin(__builtin_amdgcn_fdot2)
#define FDOT2(a, b, c) __builtin_amdgcn_fdot2((a), (b), (c), false)
#endif
#endif
#ifndef FDOT2
#define FDOT2(a, b, c) ((float)(a)[0] * (float)(b)[0] + (float)(a)[1] * (float)(b)[1] + (c))
#endif

// Extract f16x2 sub-vector `idx` (0..3) of an f16x8; callers fully unrolled
// so idx is compile-time constant (stays in registers).
__device__ __forceinline__ f16x2 get2(const f16x8 v, int idx) {
    union { f16x8 v8; f16x2 v2[4]; } u;
    u.v8 = v;
    return u.v2[idx];
}

// ---------------------------------------------------------------------------
// K1: exact f32 GEMM [x; prototypes] @ fb^T (round-1 body, proven).
// Epilogue emits f16 relu-values + 0/1 masks (masks from EXACT f32):
//   rows <  Bn: RX[b][F], BX[b][F]          row-major f16
//   rows >= Bn: RPT8/BPT8 [F/8][P][8]       8-f groups per p contiguous
// ---------------------------------------------------------------------------
__global__ __launch_bounds__(256)
void gemm_feat(const float* __restrict__ x, const float* __restrict__ prot,
               const float* __restrict__ fb,
               f16* __restrict__ RX, f16* __restrict__ BX,
               f16* __restrict__ RPT8, f16* __restrict__ BPT8)
{
    __shared__ float As[64][68];
    __shared__ float Fs[64][68];
    const int tid = threadIdx.x;
    const int rb  = blockIdx.y * 64;
    const int cb  = blockIdx.x * 64;
    const int tx  = tid & 15;
    const int ty  = tid >> 4;
    const int lr  = tid >> 2;
    const int lk  = tid & 3;

    float acc[4][4] = {};

    for (int k0 = 0; k0 < Dn; k0 += 64) {
        #pragma unroll
        for (int q = 0; q < 4; ++q) {
            const int kk = lk + q * 4;
            const int r  = rb + lr;
            const float* asrc = (r < Bn) ? (x + (size_t)r * Dn)
                                         : (prot + (size_t)(r - Bn) * Dn);
            float4 av = *(const float4*)(asrc + k0 + kk * 4);
            float4 fv = *(const float4*)(fb + (size_t)(cb + lr) * Dn + k0 + kk * 4);
            As[kk*4+0][lr] = av.x; As[kk*4+1][lr] = av.y;
            As[kk*4+2][lr] = av.z; As[kk*4+3][lr] = av.w;
            Fs[kk*4+0][lr] = fv.x; Fs[kk*4+1][lr] = fv.y;
            Fs[kk*4+2][lr] = fv.z; Fs[kk*4+3][lr] = fv.w;
        }
        __syncthreads();
        #pragma unroll 8
        for (int k = 0; k < 64; ++k) {
            float4 a = *(const float4*)&As[k][ty * 4];
            float4 f = *(const float4*)&Fs[k][tx * 4];
            const float aa[4] = {a.x, a.y, a.z, a.w};
            const float ff[4] = {f.x, f.y, f.z, f.w};
            #pragma unroll
            for (int i = 0; i < 4; ++i)
                #pragma unroll
                for (int j = 0; j < 4; ++j)
                    acc[i][j] = fmaf(aa[i], ff[j], acc[i][j]);
        }
        __syncthreads();
    }

    #pragma unroll
    for (int i = 0; i < 4; ++i) {
        const int r = rb + ty * 4 + i;
        if (r < Bn) {
            f16x4 rv, bv;
            #pragma unroll
            for (int j = 0; j < 4; ++j) {
                const float v = acc[i][j];
                rv[j] = (f16)fmaxf(v, 0.f);
                bv[j] = (v > 0.f) ? (f16)1 : (f16)0;
            }
            const size_t off = (size_t)r * Fn + cb + tx * 4;
            *(f16x4*)(RX + off) = rv;
            *(f16x4*)(BX + off) = bv;
        } else {
            const int p = r - Bn;
            #pragma unroll
            for (int j = 0; j < 4; ++j) {
                const int c = cb + tx * 4 + j;
                const float v = acc[i][j];
                const size_t off = (size_t)(c >> 3) * (Pn * 8) + p * 8 + (c & 7);
                RPT8[off] = (f16)fmaxf(v, 0.f);
                BPT8[off] = (v > 0.f) ? (f16)1 : (f16)0;
            }
        }
    }
}

// ---------------------------------------------------------------------------
// K2 v3: Tversky main, latency-optimized.
//  Block = 16b x 8p outputs x 2 F-halves = 256 threads; each thread reduces
//  F/2 = 256 features (32 f16x8 groups), then a 4KB LDS pair-reduce combines
//  halves (fixed order -> deterministic) and 128 threads write the ratio.
//  Grid (Bn/16, Pn/8) = 64 x 16 = 1024 blocks -> 4 blocks/CU, 16 waves/CU
//  (2x round-11 occupancy, half the serial load-chain per thread).
//  Math per group: I += dot2(rx,rp); M += dot2(min(rx,rp),1) (relu'd => >=0);
//  X += dot2(rx,bp); P += dot2(bx,rp) -- all f32 accumulation.
// ---------------------------------------------------------------------------
__global__ __launch_bounds__(256)
void tversky_main(const f16* __restrict__ RX, const f16* __restrict__ BX,
                  const f16* __restrict__ RPT8, const f16* __restrict__ BPT8,
                  const float* __restrict__ alpha_p, const float* __restrict__ beta_p,
                  float* __restrict__ out)
{
    __shared__ float sI[256], sM[256], sX[256], sP[256];
    const int tid  = threadIdx.x;
    const int idx  = tid & 127;          // output within tile
    const int half = tid >> 7;           // F-half
    const int b    = blockIdx.x * 16 + (idx >> 3);
    const int p    = blockIdx.y * 8 + (idx & 7);

    const f16* xrow  = RX + (size_t)b * Fn + half * (Fn / 2);
    const f16* bxrow = BX + (size_t)b * Fn + half * (Fn / 2);
    const f16* prow  = RPT8 + (size_t)(half * 32) * (Pn * 8) + (size_t)p * 8;
    const f16* bprow = BPT8 + (size_t)(half * 32) * (Pn * 8) + (size_t)p * 8;

    float aI = 0.f, aM = 0.f, aX = 0.f, aP = 0.f;
    const f16x2 one2 = {(f16)1, (f16)1};

    #pragma unroll 8
    for (int g = 0; g < 32; ++g) {
        const f16x8 rx = *(const f16x8*)(xrow  + g * 8);
        const f16x8 bx = *(const f16x8*)(bxrow + g * 8);
        const f16x8 rp = *(const f16x8*)(prow  + (size_t)g * (Pn * 8));
        const f16x8 bp = *(const f16x8*)(bprow + (size_t)g * (Pn * 8));
        const f16x8 mn = __builtin_elementwise_min(rx, rp);
        #pragma unroll
        for (int h = 0; h < 4; ++h) {
            aI = FDOT2(get2(rx, h), get2(rp, h), aI);
            aM = FDOT2(get2(mn, h), one2,        aM);
            aX = FDOT2(get2(rx, h), get2(bp, h), aX);
            aP = FDOT2(get2(bx, h), get2(rp, h), aP);
        }
    }

    sI[tid] = aI; sM[tid] = aM; sX[tid] = aX; sP[tid] = aP;
    __syncthreads();

    if (tid < 128) {
        const float I = sI[tid] + sI[tid + 128];
        const float M = sM[tid] + sM[tid + 128];
        const float X = sX[tid] + sX[tid + 128];
        const float P = sP[tid] + sP[tid + 128];
        const float alpha = *alpha_p;
        const float beta  = *beta_p;
        const float W = alpha * (X - M) + beta * (P - M);
        out[(size_t)b * Pn + p] = I / (I + W + THETA);
    }
}

extern "C" void kernel_launch(void* const* d_in, const int* in_sizes, int n_in,
                              void* d_out, int out_size, void* d_ws, size_t ws_size,
                              hipStream_t stream)
{
    const float* x     = (const float*)d_in[0];
    const float* prot  = (const float*)d_in[1];
    const float* fb    = (const float*)d_in[2];
    const float* alpha = (const float*)d_in[3];
    const float* beta  = (const float*)d_in[4];
    float* out = (float*)d_out;

    f16* RX   = (f16*)d_ws;                   // Bn*Fn
    f16* BX   = RX + (size_t)Bn * Fn;         // Bn*Fn
    f16* RPT8 = BX + (size_t)Bn * Fn;         // Fn*Pn  ([F/8][P][8])
    f16* BPT8 = RPT8 + (size_t)Fn * Pn;       // Fn*Pn

    dim3 gg(Fn / 64, (Bn + Pn) / 64);         // 8 x 18 = 144 blocks
    gemm_feat<<<gg, 256, 0, stream>>>(x, prot, fb, RX, BX, RPT8, BPT8);

    dim3 gm(Bn / 16, Pn / 8);                 // 64 x 16 = 1024 blocks
    tversky_main<<<gm, 256, 0, stream>>>(RX, BX, RPT8, BPT8, alpha, beta, out);
}

// Round 13
// 27.294 us; speedup vs baseline: 3.2751x; 1.2147x over previous
//
#include <hip/hip_runtime.h>

#define Bn 1024
#define Pn 128
#define Fn 512
#define Dn 256
#define THETA 1e-7f

typedef _Float16 f16;
typedef f16 f16x8 __attribute__((ext_vector_type(8)));
typedef f16 f16x4 __attribute__((ext_vector_type(4)));
typedef f16 f16x2 __attribute__((ext_vector_type(2)));
typedef float f32x4 __attribute__((ext_vector_type(4)));

#if defined(__has_builtin)
#if __has_builtin(__builtin_amdgcn_fdot2)
#define FDOT2(a, b, c) __builtin_amdgcn_fdot2((a), (b), (c), false)
#endif
#endif
#ifndef FDOT2
#define FDOT2(a, b, c) ((float)(a)[0] * (float)(b)[0] + (float)(a)[1] * (float)(b)[1] + (c))
#endif

// Extract f16x2 sub-vector `idx` (0..3) of an f16x8; callers fully unrolled
// so idx is compile-time constant (stays in registers).
__device__ __forceinline__ f16x2 get2(const f16x8 v, int idx) {
    union { f16x8 v8; f16x2 v2[4]; } u;
    u.v8 = v;
    return u.v2[idx];
}

// ---------------------------------------------------------------------------
// K1: exact f32 GEMM [x; prototypes] @ fb^T (round-1 body, proven).
// Epilogue emits f16 relu-values + 0/1 masks (masks from EXACT f32):
//   rows <  Bn: RX[b][F], BX[b][F]          row-major f16
//   rows >= Bn: RPT8/BPT8 [F/8][P][8]       8-f groups per p contiguous
// ---------------------------------------------------------------------------
__global__ __launch_bounds__(256)
void gemm_feat(const float* __restrict__ x, const float* __restrict__ prot,
               const float* __restrict__ fb,
               f16* __restrict__ RX, f16* __restrict__ BX,
               f16* __restrict__ RPT8, f16* __restrict__ BPT8)
{
    __shared__ float As[64][68];
    __shared__ float Fs[64][68];
    const int tid = threadIdx.x;
    const int rb  = blockIdx.y * 64;
    const int cb  = blockIdx.x * 64;
    const int tx  = tid & 15;
    const int ty  = tid >> 4;
    const int lr  = tid >> 2;
    const int lk  = tid & 3;

    float acc[4][4] = {};

    for (int k0 = 0; k0 < Dn; k0 += 64) {
        #pragma unroll
        for (int q = 0; q < 4; ++q) {
            const int kk = lk + q * 4;
            const int r  = rb + lr;
            const float* asrc = (r < Bn) ? (x + (size_t)r * Dn)
                                         : (prot + (size_t)(r - Bn) * Dn);
            float4 av = *(const float4*)(asrc + k0 + kk * 4);
            float4 fv = *(const float4*)(fb + (size_t)(cb + lr) * Dn + k0 + kk * 4);
            As[kk*4+0][lr] = av.x; As[kk*4+1][lr] = av.y;
            As[kk*4+2][lr] = av.z; As[kk*4+3][lr] = av.w;
            Fs[kk*4+0][lr] = fv.x; Fs[kk*4+1][lr] = fv.y;
            Fs[kk*4+2][lr] = fv.z; Fs[kk*4+3][lr] = fv.w;
        }
        __syncthreads();
        #pragma unroll 8
        for (int k = 0; k < 64; ++k) {
            float4 a = *(const float4*)&As[k][ty * 4];
            float4 f = *(const float4*)&Fs[k][tx * 4];
            const float aa[4] = {a.x, a.y, a.z, a.w};
            const float ff[4] = {f.x, f.y, f.z, f.w};
            #pragma unroll
            for (int i = 0; i < 4; ++i)
                #pragma unroll
                for (int j = 0; j < 4; ++j)
                    acc[i][j] = fmaf(aa[i], ff[j], acc[i][j]);
        }
        __syncthreads();
    }

    #pragma unroll
    for (int i = 0; i < 4; ++i) {
        const int r = rb + ty * 4 + i;
        if (r < Bn) {
            f16x4 rv, bv;
            #pragma unroll
            for (int j = 0; j < 4; ++j) {
                const float v = acc[i][j];
                rv[j] = (f16)fmaxf(v, 0.f);
                bv[j] = (v > 0.f) ? (f16)1 : (f16)0;
            }
            const size_t off = (size_t)r * Fn + cb + tx * 4;
            *(f16x4*)(RX + off) = rv;
            *(f16x4*)(BX + off) = bv;
        } else {
            const int p = r - Bn;
            #pragma unroll
            for (int j = 0; j < 4; ++j) {
                const int c = cb + tx * 4 + j;
                const float v = acc[i][j];
                const size_t off = (size_t)(c >> 3) * (Pn * 8) + p * 8 + (c & 7);
                RPT8[off] = (f16)fmaxf(v, 0.f);
                BPT8[off] = (v > 0.f) ? (f16)1 : (f16)0;
            }
        }
    }
}

// ---------------------------------------------------------------------------
// K2 v4: Tversky main with REGISTER TILING (2b x 4p per thread).
//  Loads per 8-f group: 12 x 16B for 64 output-f  -> 3 B/output-f
//  (round 12 was 8 B/output-f -> 537 MB issued; now 201 MB).
//  Block = 16b x 8p tile, 16 output-threads x 16 F-slices (32 f each).
//  Grid (Bn/16, Pn/8) = 1024 blocks -> 4 blocks/CU, 16 waves/CU.
//  Deterministic LDS reduce over slices; 128 threads write ratios.
// ---------------------------------------------------------------------------
__global__ __launch_bounds__(256)
void tversky_main(const f16* __restrict__ RX, const f16* __restrict__ BX,
                  const f16* __restrict__ RPT8, const f16* __restrict__ BPT8,
                  const float* __restrict__ alpha_p, const float* __restrict__ beta_p,
                  float* __restrict__ out)
{
    __shared__ f32x4 sAcc[16][128];          // [slice][outIdx] = {I,M,X,P}
    const int tid   = threadIdx.x;
    const int ot    = tid & 15;              // output-thread 0..15
    const int slice = tid >> 4;              // F-slice 0..15
    const int bt    = ot >> 1;               // 0..7
    const int pt    = ot & 1;                // 0..1
    const int bb    = blockIdx.x * 16;
    const int pb    = blockIdx.y * 8;
    const int b0    = bb + bt * 2;
    const int p0    = pb + pt * 4;
    const int g0    = slice * 4;             // first f16x8 group of this slice

    const f16* xrow0 = RX + (size_t)b0 * Fn;
    const f16* bxr0  = BX + (size_t)b0 * Fn;

    float aI[2][4] = {};
    float aM[2][4] = {};
    float aX[2][4] = {};
    float aP[2][4] = {};
    const f16x2 one2 = {(f16)1, (f16)1};

    #pragma unroll
    for (int g = 0; g < 4; ++g) {            // 4 groups of 8 f = 32 f
        const size_t xoff = (size_t)(g0 + g) * 8;
        const f16x8 rx0 = *(const f16x8*)(xrow0 + xoff);
        const f16x8 rx1 = *(const f16x8*)(xrow0 + Fn + xoff);
        const f16x8 bx0 = *(const f16x8*)(bxr0 + xoff);
        const f16x8 bx1 = *(const f16x8*)(bxr0 + Fn + xoff);
        const size_t pbase = (size_t)(g0 + g) * (Pn * 8) + (size_t)p0 * 8;
        #pragma unroll
        for (int q = 0; q < 4; ++q) {
            const f16x8 rp = *(const f16x8*)(RPT8 + pbase + q * 8);
            const f16x8 bp = *(const f16x8*)(BPT8 + pbase + q * 8);
            const f16x8 mn0 = __builtin_elementwise_min(rx0, rp);
            const f16x8 mn1 = __builtin_elementwise_min(rx1, rp);
            #pragma unroll
            for (int h = 0; h < 4; ++h) {
                const f16x2 rp2 = get2(rp, h);
                const f16x2 bp2 = get2(bp, h);
                aI[0][q] = FDOT2(get2(rx0, h), rp2,  aI[0][q]);
                aI[1][q] = FDOT2(get2(rx1, h), rp2,  aI[1][q]);
                aM[0][q] = FDOT2(get2(mn0, h), one2, aM[0][q]);
                aM[1][q] = FDOT2(get2(mn1, h), one2, aM[1][q]);
                aX[0][q] = FDOT2(get2(rx0, h), bp2,  aX[0][q]);
                aX[1][q] = FDOT2(get2(rx1, h), bp2,  aX[1][q]);
                aP[0][q] = FDOT2(get2(bx0, h), rp2,  aP[0][q]);
                aP[1][q] = FDOT2(get2(bx1, h), rp2,  aP[1][q]);
            }
        }
    }

    #pragma unroll
    for (int i = 0; i < 2; ++i) {
        #pragma unroll
        for (int q = 0; q < 4; ++q) {
            const int outIdx = (bt * 2 + i) * 8 + pt * 4 + q;
            f32x4 v = {aI[i][q], aM[i][q], aX[i][q], aP[i][q]};
            sAcc[slice][outIdx] = v;
        }
    }
    __syncthreads();

    if (tid < 128) {
        f32x4 acc = sAcc[0][tid];
        #pragma unroll
        for (int s = 1; s < 16; ++s) acc += sAcc[s][tid];
        const float alpha = *alpha_p;
        const float beta  = *beta_p;
        const float I = acc[0], M = acc[1], X = acc[2], P = acc[3];
        const float W = alpha * (X - M) + beta * (P - M);
        const int brow = tid >> 3, pcol = tid & 7;
        out[(size_t)(bb + brow) * Pn + pb + pcol] = I / (I + W + THETA);
    }
}

extern "C" void kernel_launch(void* const* d_in, const int* in_sizes, int n_in,
                              void* d_out, int out_size, void* d_ws, size_t ws_size,
                              hipStream_t stream)
{
    const float* x     = (const float*)d_in[0];
    const float* prot  = (const float*)d_in[1];
    const float* fb    = (const float*)d_in[2];
    const float* alpha = (const float*)d_in[3];
    const float* beta  = (const float*)d_in[4];
    float* out = (float*)d_out;

    f16* RX   = (f16*)d_ws;                   // Bn*Fn
    f16* BX   = RX + (size_t)Bn * Fn;         // Bn*Fn
    f16* RPT8 = BX + (size_t)Bn * Fn;         // Fn*Pn  ([F/8][P][8])
    f16* BPT8 = RPT8 + (size_t)Fn * Pn;       // Fn*Pn

    dim3 gg(Fn / 64, (Bn + Pn) / 64);         // 8 x 18 = 144 blocks
    gemm_feat<<<gg, 256, 0, stream>>>(x, prot, fb, RX, BX, RPT8, BPT8);

    dim3 gm(Bn / 16, Pn / 8);                 // 64 x 16 = 1024 blocks
    tversky_main<<<gm, 256, 0, stream>>>(RX, BX, RPT8, BPT8, alpha, beta, out);
}